// Round 4
// baseline (313.806 us; speedup 1.0000x reference)
//
#include <hip/hip_runtime.h>
#include <math.h>

#define IN_F    1024
#define NB      256
#define NL      17
#define BATCH_N 16384
#define RPB     8
#define NTRP    (NL * 4)   // trace partial slots (17 blocks x 4 waves)

typedef float v4f __attribute__((ext_vector_type(4)));

// ---------------------------------------------------------------------------
// Kernel 1: expm of 4352 4x4 matrices (f32 scaling-and-squaring + Taylor-9).
// Input norm ~0.1 -> s almost always 0, Taylor-9 error ~1e-10: matches JAX's
// f32 expm far below the harness threshold. Per-wave trace partials are
// written to fixed slots (no atomic, no memset dispatch needed).
// ---------------------------------------------------------------------------
__global__ __launch_bounds__(256) void expm_kernel(const float* __restrict__ vs,
                                                   float* __restrict__ E,
                                                   float* __restrict__ tr_part) {
    const int m = blockIdx.x * 256 + threadIdx.x;   // 0..4351 (grid exact)
    const float* v = vs + (size_t)m * 16;
    float A[16], X[16], P[16], T[16];
    #pragma unroll
    for (int i = 0; i < 16; ++i) A[i] = v[i];
    const float tr = A[0] + A[5] + A[10] + A[15];

    // 1-norm (max column abs-sum)
    float n1 = 0.0f;
    #pragma unroll
    for (int j = 0; j < 4; ++j) {
        float c = fabsf(A[j]) + fabsf(A[4 + j]) + fabsf(A[8 + j]) + fabsf(A[12 + j]);
        n1 = fmaxf(n1, c);
    }
    int s = 0;
    while (n1 > 0.25f && s < 30) { n1 *= 0.5f; ++s; }
    const float sc = __int_as_float((127 - s) << 23);   // 2^-s
    #pragma unroll
    for (int i = 0; i < 16; ++i) { A[i] *= sc; P[i] = A[i]; X[i] = A[i]; }
    X[0] += 1.0f; X[5] += 1.0f; X[10] += 1.0f; X[15] += 1.0f;

    // Taylor terms 2..9 (norm <= 0.25 -> term 9 ~ 1e-11)
    #pragma unroll 1
    for (int k = 2; k <= 9; ++k) {
        const float invk = 1.0f / (float)k;
        #pragma unroll
        for (int i = 0; i < 4; ++i)
            #pragma unroll
            for (int j = 0; j < 4; ++j)
                T[i * 4 + j] = P[i * 4 + 0] * A[0 + j] + P[i * 4 + 1] * A[4 + j] +
                               P[i * 4 + 2] * A[8 + j] + P[i * 4 + 3] * A[12 + j];
        #pragma unroll
        for (int i = 0; i < 16; ++i) { P[i] = T[i] * invk; X[i] += P[i]; }
    }
    // undo scaling: square s times
    #pragma unroll 1
    for (int q = 0; q < s; ++q) {
        #pragma unroll
        for (int i = 0; i < 4; ++i)
            #pragma unroll
            for (int j = 0; j < 4; ++j)
                T[i * 4 + j] = X[i * 4 + 0] * X[0 + j] + X[i * 4 + 1] * X[4 + j] +
                               X[i * 4 + 2] * X[8 + j] + X[i * 4 + 3] * X[12 + j];
        #pragma unroll
        for (int i = 0; i < 16; ++i) X[i] = T[i];
    }
    float* e = E + (size_t)m * 16;
    #pragma unroll
    for (int i = 0; i < 16; ++i) e[i] = X[i];

    // wave-reduce traces into a deterministic slot (no atomic)
    float tf = tr;
    #pragma unroll
    for (int off = 32; off > 0; off >>= 1) tf += __shfl_down(tf, off);
    if ((threadIdx.x & 63) == 0)
        tr_part[blockIdx.x * 4 + (threadIdx.x >> 6)] = tf;
}

// ---------------------------------------------------------------------------
// Kernel 2: fused 17-layer flow. One block = RPB rows; thread t owns features
// 4t..4t+3. z lives in registers (v4f -> v_pk_fma_f32); LDS only for the
// per-layer permutation. Next layer's E/b/idx are prefetched at the top of
// each iteration (latency drains at the following barrier).
// ---------------------------------------------------------------------------
__global__ __launch_bounds__(256, 4) void flow_kernel(const float* __restrict__ data,
                                                      const float* __restrict__ E,
                                                      const float* __restrict__ bs,
                                                      const int* __restrict__ idxs,
                                                      const float* __restrict__ tr_part,
                                                      float* __restrict__ out) {
    __shared__ float lds[RPB][IN_F];
    __shared__ float red[RPB][4];
    const int t = threadIdx.x;
    const int row0 = blockIdx.x * RPB;

    v4f z[RPB];
    #pragma unroll
    for (int r = 0; r < RPB; ++r)
        z[r] = *(const v4f*)(data + (size_t)(row0 + r) * IN_F + 4 * t);

    float ld[RPB];
    #pragma unroll
    for (int r = 0; r < RPB; ++r) ld[r] = 0.0f;

    // preload layer-0 params
    const float* ep0 = E + (size_t)t * 16;
    v4f e0 = *(const v4f*)(ep0 + 0);
    v4f e1 = *(const v4f*)(ep0 + 4);
    v4f e2 = *(const v4f*)(ep0 + 8);
    v4f e3 = *(const v4f*)(ep0 + 12);
    v4f bv = *(const v4f*)(bs + 4 * t);
    int4 id = *(const int4*)(idxs + 4 * t);

    #pragma unroll 1
    for (int l = 0; l < NL; ++l) {
        // prefetch next layer's params (clamped; drains at next barrier)
        const int ln = (l < NL - 1) ? l + 1 : l;
        const float* epn = E + ((size_t)ln * NB + t) * 16;
        const v4f ne0 = *(const v4f*)(epn + 0);
        const v4f ne1 = *(const v4f*)(epn + 4);
        const v4f ne2 = *(const v4f*)(epn + 8);
        const v4f ne3 = *(const v4f*)(epn + 12);
        const v4f nbv = *(const v4f*)(bs + (size_t)ln * IN_F + 4 * t);
        const int4 nid = *(const int4*)(idxs + (size_t)ln * IN_F + 4 * t);

        if (l > 0) {
            // bent identity + logdet partial, packed f32.
            // sum log(z/(2s)+1) over 4 elems = log prod(2s+z) - 0.5 log prod(z^2+1) - 4 ln2
            // (the -4 ln2 constant is folded into the epilogue)
            #pragma unroll
            for (int r = 0; r < RPB; ++r) {
                const v4f zz = z[r];
                const v4f q = zz * zz + 1.0f;                 // pk fma
                v4f inv;
                inv.x = rsqrtf(q.x); inv.y = rsqrtf(q.y);
                inv.z = rsqrtf(q.z); inv.w = rsqrtf(q.w);
                const v4f sq = q * inv;                       // pk mul: sqrt(z^2+1)
                const v4f num = 2.0f * sq + zz;               // pk fma
                z[r] = 0.5f * sq + (zz - 0.5f);               // pk add + pk fma
                const float pn = (num.x * num.y) * (num.z * num.w);
                const float pq = (q.x * q.y) * (q.z * q.w);
                ld[r] += __logf(pn) - 0.5f * __logf(pq);
            }
        }

        // block-diag matvec + bias (packed fma chain), stage to LDS
        #pragma unroll
        for (int r = 0; r < RPB; ++r) {
            const v4f zz = z[r];
            v4f y = bv;
            y += zz.x * e0;
            y += zz.y * e1;
            y += zz.z * e2;
            y += zz.w * e3;
            *(v4f*)(&lds[r][4 * t]) = y;
        }
        __syncthreads();

        // permutation gather
        #pragma unroll
        for (int r = 0; r < RPB; ++r) {
            v4f zn;
            zn.x = lds[r][id.x];
            zn.y = lds[r][id.y];
            zn.z = lds[r][id.z];
            zn.w = lds[r][id.w];
            z[r] = zn;
        }
        __syncthreads();

        e0 = ne0; e1 = ne1; e2 = ne2; e3 = ne3; bv = nbv; id = nid;
    }

    // write z
    float* out_z = out;
    float* out_ld = out + (size_t)BATCH_N * IN_F;
    #pragma unroll
    for (int r = 0; r < RPB; ++r)
        *(v4f*)(out_z + (size_t)(row0 + r) * IN_F + 4 * t) = z[r];

    // per-row logdet reduction (subtract the folded 16 layers * 4 ln2 per thread)
    #pragma unroll
    for (int r = 0; r < RPB; ++r) {
        float p = ld[r] - 44.36141955583649f;   // 64 * ln2
        #pragma unroll
        for (int off = 32; off > 0; off >>= 1) p += __shfl_down(p, off);
        if ((t & 63) == 0) red[r][t >> 6] = p;
    }
    __syncthreads();
    if (t < RPB) {
        float trs = 0.0f;
        #pragma unroll 1
        for (int i = 0; i < NTRP; ++i) trs += tr_part[i];
        const float ssum = red[t][0] + red[t][1] + red[t][2] + red[t][3];
        out_ld[row0 + t] = -trs - ssum;
    }
}

// ---------------------------------------------------------------------------
extern "C" void kernel_launch(void* const* d_in, const int* in_sizes, int n_in,
                              void* d_out, int out_size, void* d_ws, size_t ws_size,
                              hipStream_t stream) {
    const float* data = (const float*)d_in[0];
    const float* vs   = (const float*)d_in[1];
    const float* bs   = (const float*)d_in[2];
    const int*   idxs = (const int*)d_in[3];

    float* ws      = (float*)d_ws;
    float* tr_part = ws;          // NTRP floats (all slots written by expm)
    float* E       = ws + 128;    // 17*256*16 floats = 272 KB

    expm_kernel<<<NL, 256, 0, stream>>>(vs, E, tr_part);
    flow_kernel<<<BATCH_N / RPB, 256, 0, stream>>>(data, E, bs, idxs, tr_part, (float*)d_out);
}